// Round 11
// baseline (202.769 us; speedup 1.0000x reference)
//
#include <hip/hip_runtime.h>

// Elementwise 16-step spike recurrence:
//   v=|x|; z=0; o=0;
//   for t: v -= z*h[t]; z = (v > T[t]); o += z*d[t];
//   out = o * sign(x)
// (v-T)/(|v|+1) > 0  <=>  v > T, so the divide is eliminated. z in {0,1}
// makes z*h and z*d exact products -> bit-exact (verified rounds 1,3-10).
// Step 0 folded: T[0] < 0 <= |x| => z=1, o=d[0], v unchanged (exact).
//
// Round-11: store-path A/B. Identical to round 8 (199.8us, best) except
// stores are regular cached writes instead of __builtin_nontemporal_store.
// Theory: NT stores forgo L2 write-combining (fill kernel with regular
// stores sustains 6.7-6.9 TB/s write-only; our kernel trails the copy
// ceiling despite ~50% L3 read hits). Single-variable change.

typedef float f32x2 __attribute__((ext_vector_type(2)));
typedef float f32x4 __attribute__((ext_vector_type(4)));

// r = z*c + acc, 2 lanes/inst; c comes straight from SGPRs (wave-uniform).
__device__ __forceinline__ f32x2 pk_fma_s(f32x2 z, f32x2 c_sgpr, f32x2 acc) {
    f32x2 r;
    asm("v_pk_fma_f32 %0, %1, %2, %3" : "=v"(r) : "v"(z), "s"(c_sgpr), "v"(acc));
    return r;
}

__device__ __forceinline__ float spike_elem(float xj, const float* nh,
                                            const float* dd, const float* TT) {
    float v = fabsf(xj);
    float z = 1.0f;       // step 0 folded
    float o = dd[0];
#pragma unroll
    for (int t = 1; t < 16; ++t) {
        v = fmaf(z, nh[t], v);
        z = (v > TT[t]) ? 1.0f : 0.0f;
        o = fmaf(z, dd[t], o);
    }
    o = copysignf(o, xj);
    return (xj == 0.0f) ? 0.0f : o;
}

__global__ __launch_bounds__(256) void spike_scan_kernel(
    const float* __restrict__ x,
    const float* __restrict__ h,
    const float* __restrict__ d,
    const float* __restrict__ T,
    float* __restrict__ out,
    long long H,          // float4 pairs on the main path (n4/2)
    long long n4, long long n)
{
    // Plain uniform reads -> s_load, coefficients live in SGPRs.
    float nh[16], dd[16], TT[16];
#pragma unroll
    for (int t = 0; t < 16; ++t) {
        nh[t] = -h[t];
        dd[t] = d[t];
        TT[t] = T[t];
    }

    const long long i = (long long)blockIdx.x * blockDim.x + threadIdx.x;

    if (i < H) {
        const f32x4* __restrict__ x4 = reinterpret_cast<const f32x4*>(x);
        f32x4* __restrict__ o4 = reinterpret_cast<f32x4*>(out);

        f32x4 a = x4[i];          // cached: L3 serves the resident half
        f32x4 b = x4[i + H];

        // 4 packed chains of 2 elements each.
        f32x2 v2[4], z2[4], o2[4];
        float xs[8];
#pragma unroll
        for (int j = 0; j < 4; ++j) { xs[j] = a[j]; xs[4 + j] = b[j]; }
#pragma unroll
        for (int k = 0; k < 4; ++k) {
            v2[k][0] = fabsf(xs[2 * k]);
            v2[k][1] = fabsf(xs[2 * k + 1]);
            z2[k][0] = 1.0f; z2[k][1] = 1.0f;   // step 0 folded
            o2[k][0] = dd[0]; o2[k][1] = dd[0];
        }

#pragma unroll
        for (int t = 1; t < 16; ++t) {
            const f32x2 nhp = {nh[t], nh[t]};   // SGPR pair (uniform)
            const f32x2 ddp = {dd[t], dd[t]};
#pragma unroll
            for (int k = 0; k < 4; ++k)
                v2[k] = pk_fma_s(z2[k], nhp, v2[k]);
#pragma unroll
            for (int k = 0; k < 4; ++k) {
                z2[k][0] = (v2[k][0] > TT[t]) ? 1.0f : 0.0f;
                z2[k][1] = (v2[k][1] > TT[t]) ? 1.0f : 0.0f;
            }
#pragma unroll
            for (int k = 0; k < 4; ++k)
                o2[k] = pk_fma_s(z2[k], ddp, o2[k]);
        }

        f32x4 ra, rb;
#pragma unroll
        for (int j = 0; j < 4; ++j) {
            const float oj = o2[j / 2][j & 1];
            const float ok = o2[2 + j / 2][j & 1];
            ra[j] = (xs[j] == 0.0f) ? 0.0f : copysignf(oj, xs[j]);
            rb[j] = (xs[4 + j] == 0.0f) ? 0.0f : copysignf(ok, xs[4 + j]);
        }
        o4[i] = ra;               // A/B: regular cached stores (was NT)
        o4[i + H] = rb;
    }

    // Leftovers: float4 tiles in [2H, n4) plus scalar tail [4*n4, n).
    // (Both empty for the real shape: n = 2^27.)
    if (blockIdx.x == 0) {
        const f32x4* __restrict__ x4 = reinterpret_cast<const f32x4*>(x);
        f32x4* __restrict__ o4 = reinterpret_cast<f32x4*>(out);
        for (long long j = 2 * H + threadIdx.x; j < n4; j += blockDim.x) {
            f32x4 a = x4[j];
            f32x4 r;
#pragma unroll
            for (int q = 0; q < 4; ++q) r[q] = spike_elem(a[q], nh, dd, TT);
            o4[j] = r;
        }
        for (long long k = 4 * n4 + threadIdx.x; k < n; k += blockDim.x) {
            out[k] = spike_elem(x[k], nh, dd, TT);
        }
    }
}

extern "C" void kernel_launch(void* const* d_in, const int* in_sizes, int n_in,
                              void* d_out, int out_size, void* d_ws, size_t ws_size,
                              hipStream_t stream) {
    const float* x = (const float*)d_in[0];
    const float* h = (const float*)d_in[1];
    const float* d = (const float*)d_in[2];
    const float* T = (const float*)d_in[3];
    float* out = (float*)d_out;

    const long long n = (long long)out_size;
    const long long n4 = n / 4;
    const long long H = n4 / 2;   // 2 float4 tiles per thread

    const int block = 256;
    long long grid_ll = (H + block - 1) / block;  // exact cover
    if (grid_ll < 1) grid_ll = 1;
    const int grid = (int)grid_ll;

    spike_scan_kernel<<<grid, block, 0, stream>>>(x, h, d, T, out, H, n4, n);
}